// Round 9
// baseline (434.753 us; speedup 1.0000x reference)
//
#include <hip/hip_runtime.h>
#include <hip/hip_cooperative_groups.h>

namespace cg = cooperative_groups;

#define IN_DIM 128
#define HID    64
#define SCAN_B 256
#define RSIZE  16384      // nodes per LDS range (64 KB int counters)
#define CSHIFT 14         // edges per chunk = 16384
#define CSIZE  (1 << CSHIFT)
#define NCMAX  64

typedef __attribute__((ext_vector_type(4))) _Float16 f16x4;
typedef __attribute__((ext_vector_type(8))) _Float16 f16x8;
typedef __attribute__((ext_vector_type(4))) float    f32x4;

// ==================== cooperative single-kernel CSR build ====================
// grid = nc*nr (hist slices) + 2 (weight prep). All blocks co-resident (64KB LDS
// -> 2 blocks/CU -> 512 slots >= 436). Phases split by grid.sync().
// Offsets convention (everywhere): rowStart(v) = offsets[v] + bsums[v>>8];
// rowEnd(v) = (v==n-1) ? e : rowStart(v+1).
__global__ __launch_bounds__(256, 2) void k_build(
    const float* __restrict__ W1, const float* __restrict__ W2,
    _Float16* __restrict__ W1T, _Float16* __restrict__ W2T,
    const int* __restrict__ src, const int* __restrict__ dst,
    const float* __restrict__ ew,
    unsigned short* __restrict__ hist16, int* __restrict__ rank,
    int* __restrict__ offsets, int* __restrict__ bsums,
    int2* __restrict__ sedge, float* __restrict__ dinv,
    int n, int e, int nc, int nr, int nTiles)
{
    __shared__ int cnt[RSIZE];   // 64 KB, reused across phases
    cg::grid_group grid = cg::this_grid();
    const int nb  = nc * nr;
    const int b   = blockIdx.x;
    const int tid = threadIdx.x;

    // ---- phase A: LDS hist + rank capture; spare blocks do weight prep ----
    if (b < nb) {
        int c = b % nc, r = b / nc;
        int4* c4 = (int4*)cnt;
        #pragma unroll
        for (int k = tid; k < RSIZE / 4; k += 256) c4[k] = make_int4(0, 0, 0, 0);
        __syncthreads();
        int base = r * RSIZE;
        int i0 = c << CSHIFT;
        int i1 = min(e, i0 + CSIZE);
        for (int i = i0 + tid; i < i1; i += 256) {
            int d = dst[i];
            unsigned rel = (unsigned)(d - base);
            if (rel < RSIZE) rank[i] = atomicAdd(&cnt[rel], 1);
        }
        __syncthreads();
        size_t hb = (size_t)c * n;
        for (int j = tid; j < RSIZE; j += 256) {
            int v = base + j;
            if (v < n) hist16[hb + v] = (unsigned short)cnt[j];
        }
    } else {
        int t = (b - nb) * 256 + tid;   // 2 blocks -> stride 512
        for (int i = t; i < IN_DIM * HID; i += 512) {
            int k = i >> 6, c2 = i & 63;
            W1T[c2 * IN_DIM + k] = (_Float16)W1[i];
        }
        for (int i = t; i < HID * HID; i += 512) {
            int k = i >> 6, c2 = i & 63;
            W2T[c2 * HID + k] = (_Float16)W2[i];
        }
    }
    grid.sync();

    // ---- phase B: per-node chunk prefix + block-local scan of totals ----
    int gt = b * 256 + tid;
    int total = 0;
    if (gt < n) {
        int run = 0;
        for (int c = 0; c < nc; ++c) {
            size_t idx = (size_t)c * n + gt;
            int t0 = hist16[idx];
            hist16[idx] = (unsigned short)run;
            run += t0;
        }
        total = run;
    }
    __syncthreads();
    cnt[tid] = total;
    __syncthreads();
    for (int off = 1; off < 256; off <<= 1) {
        int t2 = (tid >= off) ? cnt[tid - off] : 0;
        __syncthreads();
        cnt[tid] += t2;
        __syncthreads();
    }
    if (gt < n) offsets[gt] = cnt[tid] - total;      // tile-local exclusive
    if (tid == 255 && b < nTiles) bsums[b] = cnt[255];
    grid.sync();

    // ---- phase C: block 0 exclusive-scans bsums (nTiles <= 512) ----
    if (b == 0) {
        int v0 = (2 * tid     < nTiles) ? bsums[2 * tid]     : 0;
        int v1 = (2 * tid + 1 < nTiles) ? bsums[2 * tid + 1] : 0;
        __syncthreads();
        cnt[tid] = v0 + v1;
        __syncthreads();
        for (int off = 1; off < 256; off <<= 1) {
            int t2 = (tid >= off) ? cnt[tid - off] : 0;
            __syncthreads();
            cnt[tid] += t2;
            __syncthreads();
        }
        int pexcl = cnt[tid] - (v0 + v1);
        if (2 * tid     < nTiles) bsums[2 * tid]     = pexcl;
        if (2 * tid + 1 < nTiles) bsums[2 * tid + 1] = pexcl + v0;
    }
    grid.sync();

    // ---- phase D: atomic-free scatter ----
    {
        int stride = gridDim.x * 256;
        for (int i = gt; i < e; i += stride) {
            int d = dst[i];
            int c = i >> CSHIFT;
            int pos = offsets[d] + bsums[d >> 8] + (int)hist16[(size_t)c * n + d] + rank[i];
            sedge[pos] = make_int2(src[i], __float_as_int(ew[i]));
        }
    }
    grid.sync();

    // ---- phase E: weighted degree -> dinv ----
    if (gt < n) {
        int s0 = offsets[gt] + bsums[gt >> 8];
        int s1 = (gt == n - 1) ? e : (offsets[gt + 1] + bsums[(gt + 1) >> 8]);
        float a = 1.0f;   // self-loop weight
        for (int j = s0; j < s1; ++j) a += __int_as_float(sedge[j].y);
        dinv[gt] = rsqrtf(a);
    }
}

// ==================== fallback multi-kernel build (same conventions) ====================

__global__ void k_prep_w(const float* __restrict__ W1, const float* __restrict__ W2,
                         _Float16* __restrict__ W1T, _Float16* __restrict__ W2T) {
    int i = blockIdx.x * blockDim.x + threadIdx.x;
    if (i < IN_DIM * HID) { int k = i >> 6, c = i & 63; W1T[c * IN_DIM + k] = (_Float16)W1[i]; }
    if (i < HID * HID)    { int k = i >> 6, c = i & 63; W2T[c * HID + k]    = (_Float16)W2[i]; }
}

__global__ __launch_bounds__(256) void k_bin_hist(const int* __restrict__ dst,
                                                  unsigned short* __restrict__ hist16,
                                                  int* __restrict__ rank,
                                                  int n, int e) {
    __shared__ int cnt[RSIZE];
    int c = blockIdx.x, r = blockIdx.y;
    int tid = threadIdx.x;
    int4* c4 = (int4*)cnt;
    #pragma unroll
    for (int k = tid; k < RSIZE / 4; k += 256) c4[k] = make_int4(0, 0, 0, 0);
    __syncthreads();
    int base = r * RSIZE;
    int i0 = c << CSHIFT;
    int i1 = min(e, i0 + CSIZE);
    for (int i = i0 + tid; i < i1; i += 256) {
        int d = dst[i];
        unsigned rel = (unsigned)(d - base);
        if (rel < RSIZE) rank[i] = atomicAdd(&cnt[rel], 1);
    }
    __syncthreads();
    size_t hb = (size_t)c * n;
    for (int j = tid; j < RSIZE; j += 256) {
        int v = base + j;
        if (v < n) hist16[hb + v] = (unsigned short)cnt[j];
    }
}

__global__ void k_chunk_scan(unsigned short* __restrict__ hist16,
                             int* __restrict__ offsets, int n, int nc) {
    int v = blockIdx.x * blockDim.x + threadIdx.x;
    if (v >= n) return;
    int run = 0;
    for (int c = 0; c < nc; ++c) {
        size_t idx = (size_t)c * n + v;
        int t = hist16[idx];
        hist16[idx] = (unsigned short)run;
        run += t;
    }
    offsets[v] = run;
}

__global__ __launch_bounds__(SCAN_B) void k_scan1(int* __restrict__ data,
                                                  int* __restrict__ blockSums, int n) {
    __shared__ int s[SCAN_B];
    int tid = threadIdx.x;
    int gid = blockIdx.x * SCAN_B + tid;
    int v = (gid < n) ? data[gid] : 0;
    s[tid] = v;
    __syncthreads();
    for (int off = 1; off < SCAN_B; off <<= 1) {
        int t = (tid >= off) ? s[tid - off] : 0;
        __syncthreads();
        s[tid] += t;
        __syncthreads();
    }
    if (gid < n) data[gid] = s[tid] - v;
    if (tid == SCAN_B - 1) blockSums[blockIdx.x] = s[tid];
}

__global__ __launch_bounds__(512) void k_scan2(int* __restrict__ blockSums, int nb) {
    __shared__ int s[512];
    int tid = threadIdx.x;
    int v = (tid < nb) ? blockSums[tid] : 0;
    s[tid] = v;
    __syncthreads();
    for (int off = 1; off < 512; off <<= 1) {
        int t = (tid >= off) ? s[tid - off] : 0;
        __syncthreads();
        s[tid] += t;
        __syncthreads();
    }
    if (tid < nb) blockSums[tid] = s[tid] - v;
}

__global__ void k_scatter_fb(const int* __restrict__ src, const int* __restrict__ dst,
                             const float* __restrict__ ew, const int* __restrict__ rank,
                             const int* __restrict__ offsets, const int* __restrict__ bsums,
                             const unsigned short* __restrict__ hist16,
                             int2* __restrict__ sedge, int n, int e) {
    int i = blockIdx.x * blockDim.x + threadIdx.x;
    if (i >= e) return;
    int d = dst[i];
    int c = i >> CSHIFT;
    int pos = offsets[d] + bsums[d >> 8] + (int)hist16[(size_t)c * n + d] + rank[i];
    sedge[pos] = make_int2(src[i], __float_as_int(ew[i]));
}

__global__ void k_deg_dinv_fb(const int* __restrict__ offsets, const int* __restrict__ bsums,
                              const int2* __restrict__ sedge, float* __restrict__ dinv,
                              int n, int e) {
    int v = blockIdx.x * blockDim.x + threadIdx.x;
    if (v >= n) return;
    int s0 = offsets[v] + bsums[v >> 8];
    int s1 = (v == n - 1) ? e : (offsets[v + 1] + bsums[(v + 1) >> 8]);
    float a = 1.0f;
    for (int j = s0; j < s1; ++j) a += __int_as_float(sedge[j].y);
    dinv[v] = rsqrtf(a);
}

// ==================== GEMMs (MFMA f16, dinv-scaled epilogue) ====================

__global__ __launch_bounds__(256) void k_gemm1(const float* __restrict__ x,
                                               const _Float16* __restrict__ W1T,
                                               const float* __restrict__ dinv,
                                               _Float16* __restrict__ h0, int n) {
    __shared__ _Float16 sX[4][16 * IN_DIM];
    int tid  = threadIdx.x;
    int wave = tid >> 6, lane = tid & 63;
    int row0 = blockIdx.x * 64 + wave * 16;
    int col  = lane & 15, kg = lane >> 4;

    f16x8 bfrag[4][4];
    #pragma unroll
    for (int ks = 0; ks < 4; ++ks)
        #pragma unroll
        for (int ct = 0; ct < 4; ++ct)
            bfrag[ks][ct] = *(const f16x8*)(W1T + (ct * 16 + col) * IN_DIM + ks * 32 + kg * 8);

    _Float16* myX = sX[wave];
    #pragma unroll
    for (int it = 0; it < 8; ++it) {
        int idx = it * 64 + lane;
        int r = idx >> 5, c4 = idx & 31;
        int grow = row0 + r;
        float4 v = make_float4(0.f, 0.f, 0.f, 0.f);
        if (grow < n) v = ((const float4*)x)[(size_t)grow * 32 + c4];
        f16x4 h; h.x = (_Float16)v.x; h.y = (_Float16)v.y; h.z = (_Float16)v.z; h.w = (_Float16)v.w;
        int off = (r * 256 + c4 * 8) ^ ((r & 7) << 4);
        *(f16x4*)((char*)myX + off) = h;
    }
    __syncthreads();

    f32x4 acc[4];
    #pragma unroll
    for (int ct = 0; ct < 4; ++ct) acc[ct] = (f32x4){0.f, 0.f, 0.f, 0.f};

    int arow = lane & 15;
    #pragma unroll
    for (int ks = 0; ks < 4; ++ks) {
        int off = (arow * 256 + kg * 16 + ks * 64) ^ ((arow & 7) << 4);
        f16x8 af = *(const f16x8*)((const char*)myX + off);
        #pragma unroll
        for (int ct = 0; ct < 4; ++ct)
            acc[ct] = __builtin_amdgcn_mfma_f32_16x16x32_f16(af, bfrag[ks][ct], acc[ct], 0, 0, 0);
    }

    int crow0 = row0 + kg * 4;
    #pragma unroll
    for (int r = 0; r < 4; ++r) {
        int gr = crow0 + r;
        if (gr < n) {
            float dv = dinv[gr];
            #pragma unroll
            for (int ct = 0; ct < 4; ++ct)
                h0[(size_t)gr * HID + ct * 16 + col] = (_Float16)(acc[ct][r] * dv);
        }
    }
}

__global__ __launch_bounds__(256) void k_gemm2(const _Float16* __restrict__ h1,
                                               const _Float16* __restrict__ W2T,
                                               const float* __restrict__ dinv,
                                               _Float16* __restrict__ h2, int n) {
    __shared__ _Float16 sX[4][16 * HID];
    int tid  = threadIdx.x;
    int wave = tid >> 6, lane = tid & 63;
    int row0 = blockIdx.x * 64 + wave * 16;
    int col  = lane & 15, kg = lane >> 4;

    f16x8 bfrag[2][4];
    #pragma unroll
    for (int ks = 0; ks < 2; ++ks)
        #pragma unroll
        for (int ct = 0; ct < 4; ++ct)
            bfrag[ks][ct] = *(const f16x8*)(W2T + (ct * 16 + col) * HID + ks * 32 + kg * 8);

    _Float16* myX = sX[wave];
    #pragma unroll
    for (int it = 0; it < 4; ++it) {
        int idx = it * 64 + lane;
        int r = idx >> 4, c4 = idx & 15;
        int grow = row0 + r;
        f16x4 h = (f16x4){0, 0, 0, 0};
        if (grow < n) h = ((const f16x4*)h1)[(size_t)grow * 16 + c4];
        int off = (r * 128 + c4 * 8) ^ ((r & 7) << 4);
        *(f16x4*)((char*)myX + off) = h;
    }
    __syncthreads();

    f32x4 acc[4];
    #pragma unroll
    for (int ct = 0; ct < 4; ++ct) acc[ct] = (f32x4){0.f, 0.f, 0.f, 0.f};

    int arow = lane & 15;
    #pragma unroll
    for (int ks = 0; ks < 2; ++ks) {
        int off = (arow * 128 + kg * 16 + ks * 64) ^ ((arow & 7) << 4);
        f16x8 af = *(const f16x8*)((const char*)myX + off);
        #pragma unroll
        for (int ct = 0; ct < 4; ++ct)
            acc[ct] = __builtin_amdgcn_mfma_f32_16x16x32_f16(af, bfrag[ks][ct], acc[ct], 0, 0, 0);
    }

    int crow0 = row0 + kg * 4;
    #pragma unroll
    for (int r = 0; r < 4; ++r) {
        int gr = crow0 + r;
        if (gr < n) {
            float dv = dinv[gr];
            #pragma unroll
            for (int ct = 0; ct < 4; ++ct)
                h2[(size_t)gr * HID + ct * 16 + col] = (_Float16)(acc[ct][r] * dv);
        }
    }
}

// ==================== CSR propagate: 8 nodes/wave, 8-deep gather batches ====================

__global__ __launch_bounds__(256) void k_prop1(const int* __restrict__ offR,
                                               const int* __restrict__ bsums,
                                               const int2* __restrict__ sedge,
                                               const _Float16* __restrict__ hin,
                                               const float* __restrict__ dinv,
                                               const float* __restrict__ b1,
                                               _Float16* __restrict__ hout, int n, int e) {
    int wave = (blockIdx.x * blockDim.x + threadIdx.x) >> 6;
    int lane = threadIdx.x & 63;
    int g    = lane >> 3;
    int gl   = lane & 7;
    int node = wave * 8 + g;
    bool valid = node < n;
    int nd = valid ? node : 0;

    int start = offR[nd] + bsums[nd >> 8];
    int end;
    if (!valid)            end = start;
    else if (nd == n - 1)  end = e;
    else                   end = offR[nd + 1] + bsums[(nd + 1) >> 8];

    float di = dinv[nd];
    float4 bbA = ((const float4*)b1)[gl * 2];
    float4 bbB = ((const float4*)b1)[gl * 2 + 1];

    f16x8 sv = *(const f16x8*)(hin + (size_t)nd * HID + gl * 8);
    float a[8];
    #pragma unroll
    for (int t = 0; t < 8; ++t) a[t] = (float)sv[t];

    int j = start;
    for (; j + 8 <= end; j += 8) {
        int2 ed[8]; f16x8 v[8]; float w[8];
        #pragma unroll
        for (int k = 0; k < 8; ++k) ed[k] = sedge[j + k];
        #pragma unroll
        for (int k = 0; k < 8; ++k) v[k] = *(const f16x8*)(hin + (size_t)ed[k].x * HID + gl * 8);
        #pragma unroll
        for (int k = 0; k < 8; ++k) w[k] = __int_as_float(ed[k].y);
        #pragma unroll
        for (int k = 0; k < 8; ++k)
            #pragma unroll
            for (int t = 0; t < 8; ++t) a[t] = fmaf((float)v[k][t], w[k], a[t]);
    }
    if (j < end) {
        #pragma unroll
        for (int k = 0; k < 8; ++k) {
            int idx = j + k;
            int cl  = idx < end ? idx : j;
            int2 ed = sedge[cl];
            float w = idx < end ? __int_as_float(ed.y) : 0.0f;
            f16x8 v = *(const f16x8*)(hin + (size_t)ed.x * HID + gl * 8);
            #pragma unroll
            for (int t = 0; t < 8; ++t) a[t] = fmaf((float)v[t], w, a[t]);
        }
    }

    if (valid) {
        f16x8 o;
        o[0] = (_Float16)fmaxf(fmaf(a[0], di, bbA.x), 0.0f);
        o[1] = (_Float16)fmaxf(fmaf(a[1], di, bbA.y), 0.0f);
        o[2] = (_Float16)fmaxf(fmaf(a[2], di, bbA.z), 0.0f);
        o[3] = (_Float16)fmaxf(fmaf(a[3], di, bbA.w), 0.0f);
        o[4] = (_Float16)fmaxf(fmaf(a[4], di, bbB.x), 0.0f);
        o[5] = (_Float16)fmaxf(fmaf(a[5], di, bbB.y), 0.0f);
        o[6] = (_Float16)fmaxf(fmaf(a[6], di, bbB.z), 0.0f);
        o[7] = (_Float16)fmaxf(fmaf(a[7], di, bbB.w), 0.0f);
        *(f16x8*)(hout + (size_t)node * HID + gl * 8) = o;
    }
}

__global__ __launch_bounds__(256) void k_prop2_final(const int* __restrict__ offR,
                                                     const int* __restrict__ bsums,
                                                     const int2* __restrict__ sedge,
                                                     const _Float16* __restrict__ hin,
                                                     const float* __restrict__ dinv,
                                                     const float* __restrict__ b2,
                                                     const float* __restrict__ Wl,
                                                     const float* __restrict__ bl,
                                                     float* __restrict__ out, int n, int e) {
    int wave = (blockIdx.x * blockDim.x + threadIdx.x) >> 6;
    int lane = threadIdx.x & 63;
    int g    = lane >> 3;
    int gl   = lane & 7;
    int node = wave * 8 + g;
    bool valid = node < n;
    int nd = valid ? node : 0;

    int start = offR[nd] + bsums[nd >> 8];
    int end;
    if (!valid)            end = start;
    else if (nd == n - 1)  end = e;
    else                   end = offR[nd + 1] + bsums[(nd + 1) >> 8];

    float di = dinv[nd];
    float4 bbA = ((const float4*)b2)[gl * 2];
    float4 bbB = ((const float4*)b2)[gl * 2 + 1];
    float4 wlA = ((const float4*)Wl)[gl * 2];
    float4 wlB = ((const float4*)Wl)[gl * 2 + 1];

    f16x8 sv = *(const f16x8*)(hin + (size_t)nd * HID + gl * 8);
    float a[8];
    #pragma unroll
    for (int t = 0; t < 8; ++t) a[t] = (float)sv[t];

    int j = start;
    for (; j + 8 <= end; j += 8) {
        int2 ed[8]; f16x8 v[8]; float w[8];
        #pragma unroll
        for (int k = 0; k < 8; ++k) ed[k] = sedge[j + k];
        #pragma unroll
        for (int k = 0; k < 8; ++k) v[k] = *(const f16x8*)(hin + (size_t)ed[k].x * HID + gl * 8);
        #pragma unroll
        for (int k = 0; k < 8; ++k) w[k] = __int_as_float(ed[k].y);
        #pragma unroll
        for (int k = 0; k < 8; ++k)
            #pragma unroll
            for (int t = 0; t < 8; ++t) a[t] = fmaf((float)v[k][t], w[k], a[t]);
    }
    if (j < end) {
        #pragma unroll
        for (int k = 0; k < 8; ++k) {
            int idx = j + k;
            int cl  = idx < end ? idx : j;
            int2 ed = sedge[cl];
            float w = idx < end ? __int_as_float(ed.y) : 0.0f;
            f16x8 v = *(const f16x8*)(hin + (size_t)ed.x * HID + gl * 8);
            #pragma unroll
            for (int t = 0; t < 8; ++t) a[t] = fmaf((float)v[t], w, a[t]);
        }
    }

    float bb[8] = {bbA.x, bbA.y, bbA.z, bbA.w, bbB.x, bbB.y, bbB.z, bbB.w};
    float wl[8] = {wlA.x, wlA.y, wlA.z, wlA.w, wlB.x, wlB.y, wlB.z, wlB.w};
    float v = 0.0f;
    #pragma unroll
    for (int t = 0; t < 8; ++t)
        v += fmaxf(fmaf(a[t], di, bb[t]), 0.0f) * wl[t];
    #pragma unroll
    for (int off = 1; off < 8; off <<= 1)
        v += __shfl_xor(v, off);
    if (valid && gl == 0) out[node] = v + bl[0];
}

// ==================== launch ====================

static inline char* align16(char* p) {
    return (char*)(((uintptr_t)p + 15) & ~(uintptr_t)15);
}

extern "C" void kernel_launch(void* const* d_in, const int* in_sizes, int n_in,
                              void* d_out, int out_size, void* d_ws, size_t ws_size,
                              hipStream_t stream) {
    const float* x   = (const float*)d_in[0];
    const int*   ei  = (const int*)d_in[1];
    const float* ew  = (const float*)d_in[2];
    const float* W1  = (const float*)d_in[3];
    const float* b1  = (const float*)d_in[4];
    const float* W2  = (const float*)d_in[5];
    const float* b2  = (const float*)d_in[6];
    const float* Wl  = (const float*)d_in[7];
    const float* bl  = (const float*)d_in[8];

    const int n = in_sizes[0] / IN_DIM;   // 100000
    const int e = in_sizes[2];            // 1000000
    const int* src = ei;
    const int* dst = ei + e;

    float* out = (float*)d_out;
    const int B256 = 256;
    const int nc = (e + CSIZE - 1) >> CSHIFT;      // 62
    const int nr = (n + RSIZE - 1) / RSIZE;        // 7
    const int nTiles = (n + 255) / 256;            // 391
    const int buildBlocks = nc * nr + 2;           // 436

    // workspace layout (16B-aligned slices)
    char* p = (char*)d_ws;
    int2*           sedge   = (int2*)p;            p += (size_t)e * 8;
    float*          dinv    = (float*)p;           p += (size_t)n * 4;
    int*            offsets = (int*)p;             p += ((size_t)n + 1) * 4;
    p = align16(p);
    int*            bsums   = (int*)p;             p += 512 * 4;
    int*            rank    = (int*)p;             p += (size_t)e * 4;
    p = align16(p);
    unsigned short* hist16  = (unsigned short*)p;  p += (size_t)NCMAX * n * 2;
    _Float16*       W1T     = (_Float16*)p;        p += IN_DIM * HID * 2;
    _Float16*       W2T     = (_Float16*)p;        p += HID * HID * 2;
    p = align16(p);
    _Float16*       A       = (_Float16*)p;        p += (size_t)n * HID * 2;
    _Float16*       B       = (_Float16*)p;        p += (size_t)n * HID * 2;

    // can all build blocks be co-resident? (needed for grid.sync)
    int dev = 0;
    hipGetDevice(&dev);
    int nCU = 0;
    hipDeviceGetAttribute(&nCU, hipDeviceAttributeMultiprocessorCount, dev);
    int maxB = 0;
    hipOccupancyMaxActiveBlocksPerMultiprocessor(&maxB, k_build, 256, 0);
    bool coop = (nCU > 0 && maxB * nCU >= buildBlocks) && nTiles <= 512;

    if (coop) {
        int n_ = n, e_ = e, nc_ = nc, nr_ = nr, nT_ = nTiles;
        void* args[] = {(void*)&W1, (void*)&W2, (void*)&W1T, (void*)&W2T,
                        (void*)&src, (void*)&dst, (void*)&ew,
                        (void*)&hist16, (void*)&rank, (void*)&offsets, (void*)&bsums,
                        (void*)&sedge, (void*)&dinv,
                        (void*)&n_, (void*)&e_, (void*)&nc_, (void*)&nr_, (void*)&nT_};
        hipLaunchCooperativeKernel(k_build, dim3(buildBlocks), dim3(256), args, 0, stream);
    } else {
        k_prep_w<<<(IN_DIM * HID + B256 - 1) / B256, B256, 0, stream>>>(W1, W2, W1T, W2T);
        dim3 binGrid(nc, nr);
        k_bin_hist<<<binGrid, B256, 0, stream>>>(dst, hist16, rank, n, e);
        k_chunk_scan<<<(n + B256 - 1) / B256, B256, 0, stream>>>(hist16, offsets, n, nc);
        k_scan1<<<nTiles, SCAN_B, 0, stream>>>(offsets, bsums, n);
        k_scan2<<<1, 512, 0, stream>>>(bsums, nTiles);
        k_scatter_fb<<<(e + B256 - 1) / B256, B256, 0, stream>>>(src, dst, ew, rank,
                                                                offsets, bsums, hist16,
                                                                sedge, n, e);
        k_deg_dinv_fb<<<(n + B256 - 1) / B256, B256, 0, stream>>>(offsets, bsums,
                                                                 sedge, dinv, n, e);
    }

    const int gemmBlocks = (n + 63) / 64;
    const int propBlocks = (n + 31) / 32;   // 32 nodes per 256-thread block

    k_gemm1<<<gemmBlocks, B256, 0, stream>>>(x, W1T, dinv, A, n);
    k_prop1<<<propBlocks, B256, 0, stream>>>(offsets, bsums, sedge, A, dinv, b1, B, n, e);

    k_gemm2<<<gemmBlocks, B256, 0, stream>>>(B, W2T, dinv, A, n);
    k_prop2_final<<<propBlocks, B256, 0, stream>>>(offsets, bsums, sedge, A, dinv,
                                                   b2, Wl, bl, out, n, e);
}

// Round 10
// 199.082 us; speedup vs baseline: 2.1838x; 2.1838x over previous
//
#include <hip/hip_runtime.h>

#define IN_DIM 128
#define HID    64
#define NCHUNK 128        // coarse pass chunks
#define BWSH   8          // bucket width = 256 nodes
#define BW     (1 << BWSH)

typedef __attribute__((ext_vector_type(4))) _Float16 f16x4;
typedef __attribute__((ext_vector_type(8))) _Float16 f16x8;
typedef __attribute__((ext_vector_type(4))) float    f32x4;

// ==================== build pass A: coarse bucket count (+ weight prep) ====================
// blocks [0,NCHUNK): LDS histogram of dst>>8 over one edge chunk -> counts[c][b]
// blocks NCHUNK..NCHUNK+1: W1/W2 -> f16 transposed
__global__ __launch_bounds__(256) void k_bcount(const int* __restrict__ dst,
                                                int* __restrict__ counts,
                                                const float* __restrict__ W1,
                                                const float* __restrict__ W2,
                                                _Float16* __restrict__ W1T,
                                                _Float16* __restrict__ W2T,
                                                int e, int nbk, int ech) {
    int c = blockIdx.x, tid = threadIdx.x;
    if (c >= NCHUNK) {
        int t = (c - NCHUNK) * 256 + tid;   // stride 512 across 2 blocks
        for (int i = t; i < IN_DIM * HID; i += 512) {
            int k = i >> 6, cc = i & 63;
            W1T[cc * IN_DIM + k] = (_Float16)W1[i];
        }
        for (int i = t; i < HID * HID; i += 512) {
            int k = i >> 6, cc = i & 63;
            W2T[cc * HID + k] = (_Float16)W2[i];
        }
        return;
    }
    __shared__ int cnt[512];
    cnt[tid] = 0; cnt[tid + 256] = 0;
    __syncthreads();
    int i0 = c * ech, i1 = min(e, i0 + ech);
    for (int i = i0 + tid; i < i1; i += 256)
        atomicAdd(&cnt[dst[i] >> BWSH], 1);
    __syncthreads();
    for (int b = tid; b < nbk; b += 256) counts[c * nbk + b] = cnt[b];
}

// ==================== build pass B: scan (counts -> starts), single block ====================
__global__ __launch_bounds__(512) void k_bscan(int* __restrict__ counts,
                                               int* __restrict__ bstart,
                                               int* __restrict__ offsets,
                                               int n, int e, int nbk) {
    __shared__ int s[512];
    int b = threadIdx.x;
    int run = 0;
    if (b < nbk) {
        for (int c = 0; c < NCHUNK; ++c) {
            int t = counts[c * nbk + b];
            counts[c * nbk + b] = run;          // chunk-local exclusive within bucket
            run += t;
        }
    }
    s[b] = run;
    __syncthreads();
    for (int off = 1; off < 512; off <<= 1) {
        int t = (b >= off) ? s[b - off] : 0;
        __syncthreads();
        s[b] += t;
        __syncthreads();
    }
    int excl = s[b] - run;                      // exclusive bucket start
    if (b < nbk) {
        bstart[b] = excl;
        for (int c = 0; c < NCHUNK; ++c) counts[c * nbk + b] += excl;
    }
    if (b == 0) { bstart[nbk] = e; offsets[n] = e; }
}

// ==================== build pass C: bucket-partition edges (LDS cursors) ====================
__global__ __launch_bounds__(256) void k_bscatter(const int* __restrict__ src,
                                                  const int* __restrict__ dst,
                                                  const float* __restrict__ ew,
                                                  const int* __restrict__ starts,
                                                  int2* __restrict__ tmpe,
                                                  unsigned short* __restrict__ tmpl,
                                                  int e, int nbk, int ech) {
    __shared__ int cur[512];
    int c = blockIdx.x, tid = threadIdx.x;
    for (int b = tid; b < nbk; b += 256) cur[b] = starts[c * nbk + b];
    __syncthreads();
    int i0 = c * ech, i1 = min(e, i0 + ech);
    for (int i = i0 + tid; i < i1; i += 256) {
        int d = dst[i];
        int b = d >> BWSH;
        int pos = atomicAdd(&cur[b], 1);
        tmpe[pos] = make_int2(src[i], __float_as_int(ew[i]));
        tmpl[pos] = (unsigned short)(d & (BW - 1));
    }
}

// ==================== build pass D: per-bucket fine sort + offsets + dinv ====================
__global__ __launch_bounds__(256) void k_bfine(const int* __restrict__ bstart,
                                               const int2* __restrict__ tmpe,
                                               const unsigned short* __restrict__ tmpl,
                                               int2* __restrict__ sedge,
                                               int* __restrict__ offsets,
                                               float* __restrict__ dinv, int n) {
    __shared__ int   cnt[256];
    __shared__ float wsum[256];
    __shared__ int   lsc[256];
    __shared__ int   cur[256];
    int b = blockIdx.x, tid = threadIdx.x;
    int bs = bstart[b], be = bstart[b + 1];
    cnt[tid] = 0; wsum[tid] = 0.0f;
    __syncthreads();
    for (int j = bs + tid; j < be; j += 256) {
        int ld = tmpl[j];
        atomicAdd(&cnt[ld], 1);
        atomicAdd(&wsum[ld], __int_as_float(tmpe[j].y));
    }
    __syncthreads();
    int v = cnt[tid];
    lsc[tid] = v;
    __syncthreads();
    for (int off = 1; off < 256; off <<= 1) {
        int t = (tid >= off) ? lsc[tid - off] : 0;
        __syncthreads();
        lsc[tid] += t;
        __syncthreads();
    }
    int excl = lsc[tid] - v;
    int node = b * BW + tid;
    if (node < n) {
        offsets[node] = bs + excl;
        dinv[node] = rsqrtf(1.0f + wsum[tid]);   // self-loop weight 1
    }
    cur[tid] = excl;
    __syncthreads();
    for (int j = bs + tid; j < be; j += 256) {
        int ld = tmpl[j];
        int pos = bs + atomicAdd(&cur[ld], 1);
        sedge[pos] = tmpe[j];
    }
}

// ==================== GEMMs (MFMA f16, dinv-scaled epilogue) ====================

__global__ __launch_bounds__(256) void k_gemm1(const float* __restrict__ x,
                                               const _Float16* __restrict__ W1T,
                                               const float* __restrict__ dinv,
                                               _Float16* __restrict__ h0, int n) {
    __shared__ _Float16 sX[4][16 * IN_DIM];
    int tid  = threadIdx.x;
    int wave = tid >> 6, lane = tid & 63;
    int row0 = blockIdx.x * 64 + wave * 16;
    int col  = lane & 15, kg = lane >> 4;

    f16x8 bfrag[4][4];
    #pragma unroll
    for (int ks = 0; ks < 4; ++ks)
        #pragma unroll
        for (int ct = 0; ct < 4; ++ct)
            bfrag[ks][ct] = *(const f16x8*)(W1T + (ct * 16 + col) * IN_DIM + ks * 32 + kg * 8);

    _Float16* myX = sX[wave];
    #pragma unroll
    for (int it = 0; it < 8; ++it) {
        int idx = it * 64 + lane;
        int r = idx >> 5, c4 = idx & 31;
        int grow = row0 + r;
        float4 v = make_float4(0.f, 0.f, 0.f, 0.f);
        if (grow < n) v = ((const float4*)x)[(size_t)grow * 32 + c4];
        f16x4 h; h.x = (_Float16)v.x; h.y = (_Float16)v.y; h.z = (_Float16)v.z; h.w = (_Float16)v.w;
        int off = (r * 256 + c4 * 8) ^ ((r & 7) << 4);
        *(f16x4*)((char*)myX + off) = h;
    }
    __syncthreads();

    f32x4 acc[4];
    #pragma unroll
    for (int ct = 0; ct < 4; ++ct) acc[ct] = (f32x4){0.f, 0.f, 0.f, 0.f};

    int arow = lane & 15;
    #pragma unroll
    for (int ks = 0; ks < 4; ++ks) {
        int off = (arow * 256 + kg * 16 + ks * 64) ^ ((arow & 7) << 4);
        f16x8 af = *(const f16x8*)((const char*)myX + off);
        #pragma unroll
        for (int ct = 0; ct < 4; ++ct)
            acc[ct] = __builtin_amdgcn_mfma_f32_16x16x32_f16(af, bfrag[ks][ct], acc[ct], 0, 0, 0);
    }

    int crow0 = row0 + kg * 4;
    #pragma unroll
    for (int r = 0; r < 4; ++r) {
        int gr = crow0 + r;
        if (gr < n) {
            float dv = dinv[gr];
            #pragma unroll
            for (int ct = 0; ct < 4; ++ct)
                h0[(size_t)gr * HID + ct * 16 + col] = (_Float16)(acc[ct][r] * dv);
        }
    }
}

__global__ __launch_bounds__(256) void k_gemm2(const _Float16* __restrict__ h1,
                                               const _Float16* __restrict__ W2T,
                                               const float* __restrict__ dinv,
                                               _Float16* __restrict__ h2, int n) {
    __shared__ _Float16 sX[4][16 * HID];
    int tid  = threadIdx.x;
    int wave = tid >> 6, lane = tid & 63;
    int row0 = blockIdx.x * 64 + wave * 16;
    int col  = lane & 15, kg = lane >> 4;

    f16x8 bfrag[2][4];
    #pragma unroll
    for (int ks = 0; ks < 2; ++ks)
        #pragma unroll
        for (int ct = 0; ct < 4; ++ct)
            bfrag[ks][ct] = *(const f16x8*)(W2T + (ct * 16 + col) * HID + ks * 32 + kg * 8);

    _Float16* myX = sX[wave];
    #pragma unroll
    for (int it = 0; it < 4; ++it) {
        int idx = it * 64 + lane;
        int r = idx >> 4, c4 = idx & 15;
        int grow = row0 + r;
        f16x4 h = (f16x4){0, 0, 0, 0};
        if (grow < n) h = ((const f16x4*)h1)[(size_t)grow * 16 + c4];
        int off = (r * 128 + c4 * 8) ^ ((r & 7) << 4);
        *(f16x4*)((char*)myX + off) = h;
    }
    __syncthreads();

    f32x4 acc[4];
    #pragma unroll
    for (int ct = 0; ct < 4; ++ct) acc[ct] = (f32x4){0.f, 0.f, 0.f, 0.f};

    int arow = lane & 15;
    #pragma unroll
    for (int ks = 0; ks < 2; ++ks) {
        int off = (arow * 128 + kg * 16 + ks * 64) ^ ((arow & 7) << 4);
        f16x8 af = *(const f16x8*)((const char*)myX + off);
        #pragma unroll
        for (int ct = 0; ct < 4; ++ct)
            acc[ct] = __builtin_amdgcn_mfma_f32_16x16x32_f16(af, bfrag[ks][ct], acc[ct], 0, 0, 0);
    }

    int crow0 = row0 + kg * 4;
    #pragma unroll
    for (int r = 0; r < 4; ++r) {
        int gr = crow0 + r;
        if (gr < n) {
            float dv = dinv[gr];
            #pragma unroll
            for (int ct = 0; ct < 4; ++ct)
                h2[(size_t)gr * HID + ct * 16 + col] = (_Float16)(acc[ct][r] * dv);
        }
    }
}

// ==================== CSR propagate: 8 nodes/wave, 8-deep gather batches ====================

__global__ __launch_bounds__(256) void k_prop1(const int* __restrict__ offR,
                                               const int2* __restrict__ sedge,
                                               const _Float16* __restrict__ hin,
                                               const float* __restrict__ dinv,
                                               const float* __restrict__ b1,
                                               _Float16* __restrict__ hout, int n) {
    int wave = (blockIdx.x * blockDim.x + threadIdx.x) >> 6;
    int lane = threadIdx.x & 63;
    int g    = lane >> 3;
    int gl   = lane & 7;
    int node = wave * 8 + g;
    bool valid = node < n;
    int nd = valid ? node : 0;

    int start = offR[nd];
    int end   = valid ? offR[nd + 1] : start;

    float di = dinv[nd];
    float4 bbA = ((const float4*)b1)[gl * 2];
    float4 bbB = ((const float4*)b1)[gl * 2 + 1];

    f16x8 sv = *(const f16x8*)(hin + (size_t)nd * HID + gl * 8);
    float a[8];
    #pragma unroll
    for (int t = 0; t < 8; ++t) a[t] = (float)sv[t];

    int j = start;
    for (; j + 8 <= end; j += 8) {
        int2 ed[8]; f16x8 v[8]; float w[8];
        #pragma unroll
        for (int k = 0; k < 8; ++k) ed[k] = sedge[j + k];
        #pragma unroll
        for (int k = 0; k < 8; ++k) v[k] = *(const f16x8*)(hin + (size_t)ed[k].x * HID + gl * 8);
        #pragma unroll
        for (int k = 0; k < 8; ++k) w[k] = __int_as_float(ed[k].y);
        #pragma unroll
        for (int k = 0; k < 8; ++k)
            #pragma unroll
            for (int t = 0; t < 8; ++t) a[t] = fmaf((float)v[k][t], w[k], a[t]);
    }
    if (j < end) {
        #pragma unroll
        for (int k = 0; k < 8; ++k) {
            int idx = j + k;
            int cl  = idx < end ? idx : j;
            int2 ed = sedge[cl];
            float w = idx < end ? __int_as_float(ed.y) : 0.0f;
            f16x8 v = *(const f16x8*)(hin + (size_t)ed.x * HID + gl * 8);
            #pragma unroll
            for (int t = 0; t < 8; ++t) a[t] = fmaf((float)v[t], w, a[t]);
        }
    }

    if (valid) {
        f16x8 o;
        o[0] = (_Float16)fmaxf(fmaf(a[0], di, bbA.x), 0.0f);
        o[1] = (_Float16)fmaxf(fmaf(a[1], di, bbA.y), 0.0f);
        o[2] = (_Float16)fmaxf(fmaf(a[2], di, bbA.z), 0.0f);
        o[3] = (_Float16)fmaxf(fmaf(a[3], di, bbA.w), 0.0f);
        o[4] = (_Float16)fmaxf(fmaf(a[4], di, bbB.x), 0.0f);
        o[5] = (_Float16)fmaxf(fmaf(a[5], di, bbB.y), 0.0f);
        o[6] = (_Float16)fmaxf(fmaf(a[6], di, bbB.z), 0.0f);
        o[7] = (_Float16)fmaxf(fmaf(a[7], di, bbB.w), 0.0f);
        *(f16x8*)(hout + (size_t)node * HID + gl * 8) = o;
    }
}

__global__ __launch_bounds__(256) void k_prop2_final(const int* __restrict__ offR,
                                                     const int2* __restrict__ sedge,
                                                     const _Float16* __restrict__ hin,
                                                     const float* __restrict__ dinv,
                                                     const float* __restrict__ b2,
                                                     const float* __restrict__ Wl,
                                                     const float* __restrict__ bl,
                                                     float* __restrict__ out, int n) {
    int wave = (blockIdx.x * blockDim.x + threadIdx.x) >> 6;
    int lane = threadIdx.x & 63;
    int g    = lane >> 3;
    int gl   = lane & 7;
    int node = wave * 8 + g;
    bool valid = node < n;
    int nd = valid ? node : 0;

    int start = offR[nd];
    int end   = valid ? offR[nd + 1] : start;

    float di = dinv[nd];
    float4 bbA = ((const float4*)b2)[gl * 2];
    float4 bbB = ((const float4*)b2)[gl * 2 + 1];
    float4 wlA = ((const float4*)Wl)[gl * 2];
    float4 wlB = ((const float4*)Wl)[gl * 2 + 1];

    f16x8 sv = *(const f16x8*)(hin + (size_t)nd * HID + gl * 8);
    float a[8];
    #pragma unroll
    for (int t = 0; t < 8; ++t) a[t] = (float)sv[t];

    int j = start;
    for (; j + 8 <= end; j += 8) {
        int2 ed[8]; f16x8 v[8]; float w[8];
        #pragma unroll
        for (int k = 0; k < 8; ++k) ed[k] = sedge[j + k];
        #pragma unroll
        for (int k = 0; k < 8; ++k) v[k] = *(const f16x8*)(hin + (size_t)ed[k].x * HID + gl * 8);
        #pragma unroll
        for (int k = 0; k < 8; ++k) w[k] = __int_as_float(ed[k].y);
        #pragma unroll
        for (int k = 0; k < 8; ++k)
            #pragma unroll
            for (int t = 0; t < 8; ++t) a[t] = fmaf((float)v[k][t], w[k], a[t]);
    }
    if (j < end) {
        #pragma unroll
        for (int k = 0; k < 8; ++k) {
            int idx = j + k;
            int cl  = idx < end ? idx : j;
            int2 ed = sedge[cl];
            float w = idx < end ? __int_as_float(ed.y) : 0.0f;
            f16x8 v = *(const f16x8*)(hin + (size_t)ed.x * HID + gl * 8);
            #pragma unroll
            for (int t = 0; t < 8; ++t) a[t] = fmaf((float)v[t], w, a[t]);
        }
    }

    float bb[8] = {bbA.x, bbA.y, bbA.z, bbA.w, bbB.x, bbB.y, bbB.z, bbB.w};
    float wl[8] = {wlA.x, wlA.y, wlA.z, wlA.w, wlB.x, wlB.y, wlB.z, wlB.w};
    float v = 0.0f;
    #pragma unroll
    for (int t = 0; t < 8; ++t)
        v += fmaxf(fmaf(a[t], di, bb[t]), 0.0f) * wl[t];
    #pragma unroll
    for (int off = 1; off < 8; off <<= 1)
        v += __shfl_xor(v, off);
    if (valid && gl == 0) out[node] = v + bl[0];
}

// ==================== launch ====================

static inline char* align16(char* p) {
    return (char*)(((uintptr_t)p + 15) & ~(uintptr_t)15);
}

extern "C" void kernel_launch(void* const* d_in, const int* in_sizes, int n_in,
                              void* d_out, int out_size, void* d_ws, size_t ws_size,
                              hipStream_t stream) {
    const float* x   = (const float*)d_in[0];
    const int*   ei  = (const int*)d_in[1];
    const float* ew  = (const float*)d_in[2];
    const float* W1  = (const float*)d_in[3];
    const float* b1  = (const float*)d_in[4];
    const float* W2  = (const float*)d_in[5];
    const float* b2  = (const float*)d_in[6];
    const float* Wl  = (const float*)d_in[7];
    const float* bl  = (const float*)d_in[8];

    const int n = in_sizes[0] / IN_DIM;   // 100000
    const int e = in_sizes[2];            // 1000000
    const int* src = ei;
    const int* dst = ei + e;

    float* out = (float*)d_out;
    const int B256 = 256;
    const int nbk = (n + BW - 1) >> BWSH;          // 391 buckets (<= 512 required)
    const int ech = (e + NCHUNK - 1) / NCHUNK;     // edges per chunk

    // workspace layout (16B-aligned slices)
    char* p = (char*)d_ws;
    int2*           sedge   = (int2*)p;            p += (size_t)e * 8;
    int2*           tmpe    = (int2*)p;            p += (size_t)e * 8;
    unsigned short* tmpl    = (unsigned short*)p;  p += (size_t)e * 2;
    p = align16(p);
    float*          dinv    = (float*)p;           p += (size_t)n * 4;
    int*            offsets = (int*)p;             p += ((size_t)n + 1) * 4;
    p = align16(p);
    int*            counts  = (int*)p;             p += (size_t)NCHUNK * nbk * 4;
    int*            bstart  = (int*)p;             p += ((size_t)nbk + 1) * 4;
    p = align16(p);
    _Float16*       W1T     = (_Float16*)p;        p += IN_DIM * HID * 2;
    _Float16*       W2T     = (_Float16*)p;        p += HID * HID * 2;
    p = align16(p);
    _Float16*       A       = (_Float16*)p;        p += (size_t)n * HID * 2;
    _Float16*       B       = (_Float16*)p;        p += (size_t)n * HID * 2;

    // build: count -> scan -> bucket-partition -> fine sort (+offsets+dinv)
    k_bcount  <<<NCHUNK + 2, B256, 0, stream>>>(dst, counts, W1, W2, W1T, W2T, e, nbk, ech);
    k_bscan   <<<1, 512, 0, stream>>>(counts, bstart, offsets, n, e, nbk);
    k_bscatter<<<NCHUNK, B256, 0, stream>>>(src, dst, ew, counts, tmpe, tmpl, e, nbk, ech);
    k_bfine   <<<nbk, B256, 0, stream>>>(bstart, tmpe, tmpl, sedge, offsets, dinv, n);

    const int gemmBlocks = (n + 63) / 64;
    const int propBlocks = (n + 31) / 32;   // 32 nodes per 256-thread block

    k_gemm1<<<gemmBlocks, B256, 0, stream>>>(x, W1T, dinv, A, n);
    k_prop1<<<propBlocks, B256, 0, stream>>>(offsets, sedge, A, dinv, b1, B, n);

    k_gemm2<<<gemmBlocks, B256, 0, stream>>>(B, W2T, dinv, A, n);
    k_prop2_final<<<propBlocks, B256, 0, stream>>>(offsets, sedge, A, dinv,
                                                   b2, Wl, bl, out, n);
}